// Round 6
// baseline (51.918 us; speedup 1.0000x reference)
//
#include <hip/hip_runtime.h>
#include <hip/hip_bf16.h>
#include <math.h>

// TopKRouter: x (16384 x 2048) f32 @ gate_w^T (2048 x 64) -> top-2 + softmax.
// Output (f32): [indices as floats (N*2)] ++ [weights (N*2)].
//
// v6: latency-bound fix = max concurrency. 1024 blocks x 4 waves, 16 waves/CU
// (4 blocks/CU), BM=16 rows, waves split K (512 each). A loads direct to VGPR
// (no LDS staging, no barriers in main loop, each wave self-paced). w packed
// once to bf16 hi/lo ([g][hi64|lo64][e] -> contiguous 256B runs, zero split
// VALU in main loop). 3-term split MFMA (err ~1e-6). LDS reduce + shfl top-2.

constexpr int D_DIM  = 2048;
constexpr int E_DIM  = 64;
constexpr int BM     = 16;              // rows per block
constexpr int KSLICE = D_DIM / 4;       // 512 per wave
constexpr int KSTEPS = KSLICE / 32;     // 16
constexpr int LPAD   = 68;              // logits row stride (f32)

typedef __attribute__((ext_vector_type(8))) short s16x8;  // 8 bf16
typedef __attribute__((ext_vector_type(4))) float f32x4;  // MFMA C/D

static __device__ __forceinline__ short f2bf(float f) {
    __hip_bfloat16 h = __float2bfloat16(f);   // RNE
    return *reinterpret_cast<short*>(&h);
}
static __device__ __forceinline__ float b2f(short s) {
    union { unsigned u; float f; } x;
    x.u = ((unsigned)(unsigned short)s) << 16;
    return x.f;
}

// pack w -> [g (k>>3)][hi: e 0..63 | lo: e 0..63][8 bf16], g=0..255
__global__ __launch_bounds__(256, 1)
void pack_w(const float* __restrict__ w, short* __restrict__ wsb) {
    const int idx = blockIdx.x * 256 + threadIdx.x;   // 64*2048
    const int e = idx >> 11, k = idx & 2047;
    const float v = w[idx];
    const short hi = f2bf(v);
    const short lo = f2bf(v - b2f(hi));
    const int g = k >> 3, j = k & 7;
    const size_t base = ((size_t)g * 128 + e) * 8 + j;
    wsb[base]           = hi;
    wsb[base + 64 * 8]  = lo;
}

template <bool PACKED>
__global__ __launch_bounds__(256, 4)
void router_v6(const float* __restrict__ x,
               const float* __restrict__ w,
               const short* __restrict__ wsb,
               float* __restrict__ out,
               int nrows) {
    __shared__ alignas(16) float lgs[4][BM][LPAD];   // 17.4 KB

    const int t    = threadIdx.x;
    const int lane = t & 63;
    const int wv   = t >> 6;            // wave id -> K-slice
    const int row0 = blockIdx.x * BM;
    const int l15  = lane & 15;
    const int k8   = lane >> 4;         // 8-k group within K=32
    const int k0   = wv * KSLICE;
    const int ph   = blockIdx.x & (KSTEPS - 1);   // K-phase rotation

    f32x4 acc[4];
    #pragma unroll
    for (int nf = 0; nf < 4; ++nf)
        #pragma unroll
        for (int j = 0; j < 4; ++j) acc[nf][j] = 0.f;

    const float* __restrict__ px0 = x + (size_t)(row0 + l15) * D_DIM;

    #pragma unroll 2
    for (int s0 = 0; s0 < KSTEPS; ++s0) {
        const int s  = (s0 + ph) & (KSTEPS - 1);
        const int kk = k0 + s * 32 + k8 * 8;
        // ---- A fragment: 8 consecutive f32 of this lane's row, split hi/lo ----
        const float4 v0 = *reinterpret_cast<const float4*>(px0 + kk);
        const float4 v1 = *reinterpret_cast<const float4*>(px0 + kk + 4);
        const float vv[8] = {v0.x, v0.y, v0.z, v0.w, v1.x, v1.y, v1.z, v1.w};
        s16x8 ah, al;
        #pragma unroll
        for (int j = 0; j < 8; ++j) {
            const short h = f2bf(vv[j]);
            ah[j] = h;
            al[j] = f2bf(vv[j] - b2f(h));
        }
        // ---- B fragments: packed hi/lo (contiguous 256B runs, L2-resident) ----
        s16x8 bh[4], bl[4];
        const int g = kk >> 3;
        #pragma unroll
        for (int nf = 0; nf < 4; ++nf) {
            if (PACKED) {
                const short* pw = wsb + ((size_t)g * 128 + nf * 16 + l15) * 8;
                bh[nf] = *reinterpret_cast<const s16x8*>(pw);
                bl[nf] = *reinterpret_cast<const s16x8*>(pw + 512);
            } else {
                const float* pw = w + (size_t)(nf * 16 + l15) * D_DIM + kk;
                const float4 w0 = *reinterpret_cast<const float4*>(pw);
                const float4 w1 = *reinterpret_cast<const float4*>(pw + 4);
                const float wvv[8] = {w0.x, w0.y, w0.z, w0.w, w1.x, w1.y, w1.z, w1.w};
                #pragma unroll
                for (int j = 0; j < 8; ++j) {
                    const short h = f2bf(wvv[j]);
                    bh[nf][j] = h;
                    bl[nf][j] = f2bf(wvv[j] - b2f(h));
                }
            }
        }
        // ---- 3-term split MFMA ----
        #pragma unroll
        for (int nf = 0; nf < 4; ++nf) {
            acc[nf] = __builtin_amdgcn_mfma_f32_16x16x32_bf16(al, bh[nf], acc[nf], 0, 0, 0);
            acc[nf] = __builtin_amdgcn_mfma_f32_16x16x32_bf16(ah, bl[nf], acc[nf], 0, 0, 0);
            acc[nf] = __builtin_amdgcn_mfma_f32_16x16x32_bf16(ah, bh[nf], acc[nf], 0, 0, 0);
        }
    }

    // ---- partials -> LDS. C/D layout: col = lane&15, row = (lane>>4)*4+reg ----
    #pragma unroll
    for (int nf = 0; nf < 4; ++nf)
        #pragma unroll
        for (int j = 0; j < 4; ++j)
            lgs[wv][k8 * 4 + j][nf * 16 + l15] = acc[nf][j];
    __syncthreads();

    // ---- reduce 4 K-partials + per-row top-2 + softmax (waves 0,1) ----
    if (wv < 2) {
        const int row8 = lane >> 3;
        const int seg  = lane & 7;
        const int row  = wv * 8 + row8;     // 0..15
        float sv[8];
        #pragma unroll
        for (int j = 0; j < 8; ++j) sv[j] = 0.f;
        #pragma unroll
        for (int p = 0; p < 4; ++p) {
            const float* rp = &lgs[p][row][seg * 8];
            const float4 a  = *reinterpret_cast<const float4*>(rp);
            const float4 bq = *reinterpret_cast<const float4*>(rp + 4);
            sv[0] += a.x;  sv[1] += a.y;  sv[2] += a.z;  sv[3] += a.w;
            sv[4] += bq.x; sv[5] += bq.y; sv[6] += bq.z; sv[7] += bq.w;
        }
        float m1 = sv[0]; int i1 = seg * 8;
        float m2 = -INFINITY; int i2 = 0;
        #pragma unroll
        for (int j = 1; j < 8; ++j) {
            const float v = sv[j]; const int idx = seg * 8 + j;
            if (v > m1)      { m2 = m1; i2 = i1; m1 = v; i1 = idx; }
            else if (v > m2) { m2 = v;  i2 = idx; }
        }
        #pragma unroll
        for (int d = 1; d < 8; d <<= 1) {
            const float M1 = __shfl_xor(m1, d); const int I1 = __shfl_xor(i1, d);
            const float M2 = __shfl_xor(m2, d); const int I2 = __shfl_xor(i2, d);
            const bool sw = (M1 > m1) || (M1 == m1 && I1 < i1);
            const float a1 = sw ? M1 : m1; const int j1 = sw ? I1 : i1;
            const float b1 = sw ? m1 : M1; const int kx = sw ? i1 : I1;
            const float a2 = sw ? M2 : m2; const int j2 = sw ? I2 : i2;
            const bool t2 = (b1 > a2) || (b1 == a2 && kx < j2);
            m1 = a1; i1 = j1;
            m2 = t2 ? b1 : a2; i2 = t2 ? kx : j2;
        }
        if (seg == 0) {
            const float e2v = expf(m2 - m1);
            const float sm  = 1.0f + e2v;
            const long  r   = row0 + row;
            const long  off = (long)nrows * 2;
            out[2 * r + 0]       = (float)i1;
            out[2 * r + 1]       = (float)i2;
            out[off + 2 * r + 0] = 1.0f / sm;
            out[off + 2 * r + 1] = e2v / sm;
        }
    }
}

extern "C" void kernel_launch(void* const* d_in, const int* in_sizes, int n_in,
                              void* d_out, int out_size, void* d_ws, size_t ws_size,
                              hipStream_t stream) {
    const float* x = (const float*)d_in[0];
    const float* w = (const float*)d_in[1];
    float* out = (float*)d_out;
    short* wsb = (short*)d_ws;
    const int nrows = in_sizes[0] / D_DIM;            // 16384
    const int grid  = nrows / BM;                     // 1024
    const bool packed = ws_size >= (size_t)(E_DIM * D_DIM) * 2 * sizeof(short);

    if (packed) {
        hipLaunchKernelGGL(pack_w, dim3(E_DIM * D_DIM / 256), dim3(256), 0, stream, w, wsb);
        hipLaunchKernelGGL(router_v6<true>, dim3(grid), dim3(256), 0, stream,
                           x, w, wsb, out, nrows);
    } else {
        hipLaunchKernelGGL(router_v6<false>, dim3(grid), dim3(256), 0, stream,
                           x, w, wsb, out, nrows);
    }
}

// Round 7
// 42.194 us; speedup vs baseline: 1.2305x; 1.2305x over previous
//
#include <hip/hip_runtime.h>
#include <hip/hip_bf16.h>
#include <math.h>

// TopKRouter: x (16384 x 2048) f32 @ gate_w^T (2048 x 64) -> top-2 + softmax.
// Output (f32): [indices as floats (N*2)] ++ [weights (N*2)].
//
// v7: pure-read machine. Compute has ZERO VMEM: A (f32, swizzled source) and
// B (bf16 hi/lo, pre-packed) both staged via global_load_lds; per-wave
// vmcnt(3) counts exactly the next chunk's 3 staging instrs -> clean depth-2
// pipeline. 8 waves: wave = 16 rows x 16 experts (E-split, no K-partials).
// 3-term split-bf16 MFMA (err ~1e-6). 2 blocks/CU. Shfl top-2 epilogue.

constexpr int D_DIM = 2048;
constexpr int E_DIM = 64;
constexpr int BM    = 32;               // rows per block
constexpr int BKC   = 64;               // K per chunk
constexpr int NCH   = D_DIM / BKC;      // 32 chunks
constexpr int CHF   = BM * BKC / 2 + BKC * E_DIM / 2;  // unused-doc
constexpr int LPAD  = 68;

typedef __attribute__((ext_vector_type(8))) short s16x8;  // 8 bf16
typedef __attribute__((ext_vector_type(4))) float f32x4;  // MFMA C/D

static __device__ __forceinline__ short f2bf(float f) {
    __hip_bfloat16 h = __float2bfloat16(f);   // RNE
    return *reinterpret_cast<short*>(&h);
}
static __device__ __forceinline__ float b2f(short s) {
    union { unsigned u; float f; } x;
    x.u = ((unsigned)(unsigned short)s) << 16;
    return x.f;
}

// pack w -> per k-group g (8 k's): [g][hi: e0..63 x 8bf16 | lo: e0..63 x 8bf16]
// -> each K=64 chunk of B is a contiguous 16KB run (8 g's x 2KB).
__global__ __launch_bounds__(256, 1)
void pack_w(const float* __restrict__ w, short* __restrict__ wsb) {
    const int idx = blockIdx.x * 256 + threadIdx.x;   // 64*2048
    const int e = idx >> 11, k = idx & 2047;
    const float v = w[idx];
    const short hi = f2bf(v);
    const short lo = f2bf(v - b2f(hi));
    const int g = k >> 3, j = k & 7;
    const size_t base = (size_t)g * 1024 + e * 8 + j;   // shorts
    wsb[base]       = hi;
    wsb[base + 512] = lo;
}

template <bool PACKED>
__global__ __launch_bounds__(512, 4)
void router_v7(const float* __restrict__ x,
               const float* __restrict__ w,
               const short* __restrict__ wsb,
               float* __restrict__ out,
               int nrows) {
    // chunk = A: 32 rows x 256B (8KB) | B: 8 g x 2KB (16KB) -> 24KB; dbuf 48KB
    __shared__ alignas(16) float smem[2][6144];

    const int t    = threadIdx.x;
    const int lane = t & 63;
    const int wv   = t >> 6;            // 8 waves
    const int row0 = blockIdx.x * BM;
    const int l15  = lane & 15;
    const int k8   = lane >> 4;
    const int rsel = wv & 1;            // row group: rows [16*rsel, +16)
    const int e0w  = (wv >> 1) * 16;    // expert group: [e0w, e0w+16)
    const int ph   = blockIdx.x & (NCH - 1);

    // ---- staging: 24 gll instrs per chunk (A:8, B:16), 3 per wave ----
    auto stage = [&](int b, int cc) {
        #pragma unroll
        for (int q = 0; q < 3; ++q) {
            const int i = wv * 3 + q;          // 0..23
            const char* src;
            if (i < 8) {                        // A: rows 4i..4i+3, swizzled src
                const int r = 4 * i + (lane >> 4);
                src = (const char*)x + (size_t)(row0 + r) * (D_DIM * 4)
                    + cc * 256 + (((lane & 15) * 16) ^ ((r & 7) << 4));
            } else {                            // B: contiguous 16KB run
                const int j = i - 8;            // 0..15
                if (PACKED)
                    src = (const char*)wsb + (size_t)cc * 16384 + j * 1024 + lane * 16;
                else {
                    // raw f32 B: [g][e][8 f32]; instr j: g=j>>1, e=(j&1)*32+(l>>1)
                    const int gl = j >> 1;
                    const int e  = (j & 1) * 32 + (lane >> 1);
                    src = (const char*)w + (size_t)e * (D_DIM * 4)
                        + (cc * BKC + gl * 8) * 4 + (lane & 1) * 16;
                }
            }
            __builtin_amdgcn_global_load_lds(
                (const __attribute__((address_space(1))) void*)src,
                (__attribute__((address_space(3))) void*)((char*)&smem[b][0] + i * 1024),
                16, 0, 0);
        }
    };

    f32x4 acc;
    #pragma unroll
    for (int j = 0; j < 4; ++j) acc[j] = 0.f;

    auto compute = [&](int b) {
        const char* Ab = (const char*)&smem[b][0];
        const char* Bb = Ab + 8192;
        const int r    = 16 * rsel + l15;
        const int swz  = (r & 7) << 4;
        #pragma unroll
        for (int s = 0; s < 2; ++s) {           // 2 K=32 steps per chunk
            const int gl  = s * 4 + k8;         // k-group 0..7
            // ---- A frag: 8 f32 of row r, split hi/lo ----
            const char* rp = Ab + r * 256;
            const int off  = s * 128 + k8 * 32;
            const float4 v0 = *reinterpret_cast<const float4*>(rp + (off ^ swz));
            const float4 v1 = *reinterpret_cast<const float4*>(rp + ((off + 16) ^ swz));
            const float vv[8] = {v0.x, v0.y, v0.z, v0.w, v1.x, v1.y, v1.z, v1.w};
            s16x8 ah, al;
            #pragma unroll
            for (int j = 0; j < 8; ++j) {
                const short h = f2bf(vv[j]);
                ah[j] = h;
                al[j] = f2bf(vv[j] - b2f(h));
            }
            // ---- B frag (this wave's 16 experts) ----
            s16x8 bh, bl;
            if (PACKED) {
                const char* bp = Bb + gl * 2048 + (e0w + l15) * 16;
                bh = *reinterpret_cast<const s16x8*>(bp);
                bl = *reinterpret_cast<const s16x8*>(bp + 1024);
            } else {
                const char* bp = Bb + ((size_t)gl * 64 + e0w + l15) * 32;
                const float4 w0 = *reinterpret_cast<const float4*>(bp);
                const float4 w1 = *reinterpret_cast<const float4*>(bp + 16);
                const float wvv[8] = {w0.x, w0.y, w0.z, w0.w, w1.x, w1.y, w1.z, w1.w};
                #pragma unroll
                for (int j = 0; j < 8; ++j) {
                    const short h = f2bf(wvv[j]);
                    bh[j] = h;
                    bl[j] = f2bf(wvv[j] - b2f(h));
                }
            }
            // ---- 3-term split MFMA ----
            acc = __builtin_amdgcn_mfma_f32_16x16x32_bf16(al, bh, acc, 0, 0, 0);
            acc = __builtin_amdgcn_mfma_f32_16x16x32_bf16(ah, bl, acc, 0, 0, 0);
            acc = __builtin_amdgcn_mfma_f32_16x16x32_bf16(ah, bh, acc, 0, 0, 0);
        }
    };

    // ---- depth-2 counted pipeline: per-wave vmcnt counts ONLY staging ----
    stage(0, ph);
    stage(1, (ph + 1) & (NCH - 1));
    #pragma unroll 1
    for (int c = 0; c < NCH; ++c) {
        if (c + 1 < NCH) asm volatile("s_waitcnt vmcnt(3)" ::: "memory");
        else             asm volatile("s_waitcnt vmcnt(0)" ::: "memory");
        __builtin_amdgcn_s_barrier();           // all 24 instrs of chunk c done
        asm volatile("" ::: "memory");
        compute(c & 1);
        asm volatile("s_waitcnt lgkmcnt(0)" ::: "memory");
        __builtin_amdgcn_s_barrier();           // all reads of buf[c&1] done
        asm volatile("" ::: "memory");
        if (c + 2 < NCH) stage(c & 1, (c + 2 + ph) & (NCH - 1));
    }

    // ---- logits -> LDS (reduction-free: each (row,e) written once) ----
    float* lgs = &smem[0][0];                   // [32][68] = 8.7 KB
    #pragma unroll
    for (int j = 0; j < 4; ++j)
        lgs[(16 * rsel + k8 * 4 + j) * LPAD + e0w + l15] = acc[j];
    __syncthreads();

    // ---- per-row top-2 + softmax (waves 0..3, 8 rows each) ----
    if (wv < 4) {
        const int row = wv * 8 + (lane >> 3);
        const int seg = lane & 7;
        const float* rp = &lgs[row * LPAD + seg * 8];
        const float4 a  = *reinterpret_cast<const float4*>(rp);
        const float4 bq = *reinterpret_cast<const float4*>(rp + 4);
        const float sv[8] = {a.x, a.y, a.z, a.w, bq.x, bq.y, bq.z, bq.w};
        float m1 = sv[0]; int i1 = seg * 8;
        float m2 = -INFINITY; int i2 = 0;
        #pragma unroll
        for (int j = 1; j < 8; ++j) {
            const float v = sv[j]; const int idx = seg * 8 + j;
            if (v > m1)      { m2 = m1; i2 = i1; m1 = v; i1 = idx; }
            else if (v > m2) { m2 = v;  i2 = idx; }
        }
        #pragma unroll
        for (int d = 1; d < 8; d <<= 1) {
            const float M1 = __shfl_xor(m1, d); const int I1 = __shfl_xor(i1, d);
            const float M2 = __shfl_xor(m2, d); const int I2 = __shfl_xor(i2, d);
            const bool sw = (M1 > m1) || (M1 == m1 && I1 < i1);
            const float a1 = sw ? M1 : m1; const int j1 = sw ? I1 : i1;
            const float b1 = sw ? m1 : M1; const int kx = sw ? i1 : I1;
            const float a2 = sw ? M2 : m2; const int j2 = sw ? I2 : i2;
            const bool t2 = (b1 > a2) || (b1 == a2 && kx < j2);
            m1 = a1; i1 = j1;
            m2 = t2 ? b1 : a2; i2 = t2 ? kx : j2;
        }
        if (seg == 0) {
            const float e2v = expf(m2 - m1);
            const float sm  = 1.0f + e2v;
            const long  r   = row0 + row;
            const long  off = (long)nrows * 2;
            out[2 * r + 0]       = (float)i1;
            out[2 * r + 1]       = (float)i2;
            out[off + 2 * r + 0] = 1.0f / sm;
            out[off + 2 * r + 1] = e2v / sm;
        }
    }
}

extern "C" void kernel_launch(void* const* d_in, const int* in_sizes, int n_in,
                              void* d_out, int out_size, void* d_ws, size_t ws_size,
                              hipStream_t stream) {
    const float* x = (const float*)d_in[0];
    const float* w = (const float*)d_in[1];
    float* out = (float*)d_out;
    short* wsb = (short*)d_ws;
    const int nrows = in_sizes[0] / D_DIM;            // 16384
    const int grid  = nrows / BM;                     // 512
    const bool packed = ws_size >= (size_t)(E_DIM * D_DIM) * 2 * sizeof(short);

    if (packed) {
        hipLaunchKernelGGL(pack_w, dim3(E_DIM * D_DIM / 256), dim3(256), 0, stream, w, wsb);
        hipLaunchKernelGGL(router_v7<true>, dim3(grid), dim3(512), 0, stream,
                           x, w, wsb, out, nrows);
    } else {
        hipLaunchKernelGGL(router_v7<false>, dim3(grid), dim3(512), 0, stream,
                           x, w, wsb, out, nrows);
    }
}

// Round 8
// 41.054 us; speedup vs baseline: 1.2646x; 1.0278x over previous
//
#include <hip/hip_runtime.h>
#include <hip/hip_bf16.h>
#include <math.h>

// TopKRouter: x (16384 x 2048) f32 @ gate_w^T (2048 x 64) -> top-2 + softmax.
// Output (f32): [indices as floats (N*2)] ++ [weights (N*2)].
//
// v8: A-only LDS (gll staged, swizzled source, depth-4); B prefetched to
// REGISTERS from L2 (packed bf16 hi/lo, 4 rotating sets, static indices).
// Exactly 5 VMEM/chunk/wave -> clean vmcnt(15) depth-4 pipeline, peeled
// tail 15/10/5/0. 8 waves x (16 rows x 16 experts), 2 blocks/CU.
// 3-term split-bf16 MFMA (err ~1e-6). Shfl top-2 epilogue.

constexpr int D_DIM = 2048;
constexpr int E_DIM = 64;
constexpr int BM    = 32;               // rows per block
constexpr int BKC   = 64;               // K per chunk
constexpr int NCH   = D_DIM / BKC;      // 32 chunks
constexpr int LPAD  = 68;

typedef __attribute__((ext_vector_type(8))) short s16x8;  // 8 bf16
typedef __attribute__((ext_vector_type(4))) float f32x4;  // MFMA C/D

static __device__ __forceinline__ short f2bf(float f) {
    __hip_bfloat16 h = __float2bfloat16(f);   // RNE
    return *reinterpret_cast<short*>(&h);
}
static __device__ __forceinline__ float b2f(short s) {
    union { unsigned u; float f; } x;
    x.u = ((unsigned)(unsigned short)s) << 16;
    return x.f;
}

template <int N> static __device__ __forceinline__ void waitvm() {
    asm volatile("s_waitcnt vmcnt(%0)" :: "n"(N) : "memory");
}

// pack w -> per k-group g (8 k's): [g][hi: e0..63 x 8bf16 | lo: e0..63 x 8bf16]
__global__ __launch_bounds__(256, 1)
void pack_w(const float* __restrict__ w, short* __restrict__ wsb) {
    const int idx = blockIdx.x * 256 + threadIdx.x;   // 64*2048
    const int e = idx >> 11, k = idx & 2047;
    const float v = w[idx];
    const short hi = f2bf(v);
    const short lo = f2bf(v - b2f(hi));
    const int g = k >> 3, j = k & 7;
    const size_t base = (size_t)g * 1024 + e * 8 + j;   // shorts
    wsb[base]       = hi;
    wsb[base + 512] = lo;
}

template <bool PACKED>
__global__ __launch_bounds__(512, 4)
void router_v8(const float* __restrict__ x,
               const float* __restrict__ w,
               const short* __restrict__ wsb,
               float* __restrict__ out,
               int nrows) {
    __shared__ alignas(16) float smem[4][BM * BKC / 4 * 4];  // 4 x 8KB

    const int t    = threadIdx.x;
    const int lane = t & 63;
    const int wv   = t >> 6;            // 8 waves
    const int row0 = blockIdx.x * BM;
    const int l15  = lane & 15;
    const int k8   = lane >> 4;
    const int rsel = wv & 1;            // rows [16*rsel, +16)
    const int e0w  = (wv >> 1) * 16;    // experts [e0w, +16)
    const int ph   = blockIdx.x & (NCH - 1);
    const char* wsb_b = (const char*)wsb;

    s16x8 Bh[4][2], Bl[4][2];           // 4 rotating sets (static idx via unroll)

    auto loadB = [&](int p, int c) {
        const int cc = (c + ph) & (NCH - 1);
        if constexpr (PACKED) {
            #pragma unroll
            for (int s = 0; s < 2; ++s) {
                const char* bp = wsb_b + (size_t)cc * 16384
                               + (s * 4 + k8) * 2048 + (e0w + l15) * 16;
                Bh[p][s] = *reinterpret_cast<const s16x8*>(bp);
                Bl[p][s] = *reinterpret_cast<const s16x8*>(bp + 1024);
            }
        } else {
            #pragma unroll
            for (int s = 0; s < 2; ++s) {
                const float* pw = w + (size_t)(e0w + l15) * D_DIM
                                + cc * BKC + (s * 4 + k8) * 8;
                const float4 w0 = *reinterpret_cast<const float4*>(pw);
                const float4 w1 = *reinterpret_cast<const float4*>(pw + 4);
                const float wvv[8] = {w0.x, w0.y, w0.z, w0.w, w1.x, w1.y, w1.z, w1.w};
                #pragma unroll
                for (int j = 0; j < 8; ++j) {
                    const short h = f2bf(wvv[j]);
                    Bh[p][s][j] = h;
                    Bl[p][s][j] = f2bf(wvv[j] - b2f(h));
                }
            }
        }
    };

    // A staging: wave wv stages rows [4wv, 4wv+4) of the chunk; dst is
    // wave-uniform (rule #21: linear dest, pre-swizzled source).
    auto stageA = [&](int p, int c) {
        const int cc = (c + ph) & (NCH - 1);
        const int r  = 4 * wv + (lane >> 4);
        const char* src = (const char*)x + (size_t)(row0 + r) * (D_DIM * 4)
                        + cc * 256 + ((l15 * 16) ^ ((r & 7) << 4));
        __builtin_amdgcn_global_load_lds(
            (const __attribute__((address_space(1))) void*)src,
            (__attribute__((address_space(3))) void*)((char*)&smem[p][0] + wv * 1024),
            16, 0, 0);
    };

    f32x4 acc;
    #pragma unroll
    for (int j = 0; j < 4; ++j) acc[j] = 0.f;

    auto compute = [&](int p) {
        const char* rp  = (const char*)&smem[p][0] + (16 * rsel + l15) * 256;
        const int   swz = ((16 * rsel + l15) & 7) << 4;
        #pragma unroll
        for (int s = 0; s < 2; ++s) {
            const int off = s * 128 + k8 * 32;
            const float4 v0 = *reinterpret_cast<const float4*>(rp + (off ^ swz));
            const float4 v1 = *reinterpret_cast<const float4*>(rp + ((off + 16) ^ swz));
            const float vv[8] = {v0.x, v0.y, v0.z, v0.w, v1.x, v1.y, v1.z, v1.w};
            s16x8 ah, al;
            #pragma unroll
            for (int j = 0; j < 8; ++j) {
                const short h = f2bf(vv[j]);
                ah[j] = h;
                al[j] = f2bf(vv[j] - b2f(h));
            }
            acc = __builtin_amdgcn_mfma_f32_16x16x32_bf16(al, Bh[p][s], acc, 0, 0, 0);
            acc = __builtin_amdgcn_mfma_f32_16x16x32_bf16(ah, Bl[p][s], acc, 0, 0, 0);
            acc = __builtin_amdgcn_mfma_f32_16x16x32_bf16(ah, Bh[p][s], acc, 0, 0, 0);
        }
    };

    // ---- prologue: stage chunks 0..3 (5 VMEM ops each per wave) ----
    #pragma unroll
    for (int p = 0; p < 4; ++p) { loadB(p, p); stageA(p, p); }

    // ---- main: chunks 0..27, depth-4, vmcnt(15) steady state ----
    #pragma unroll 1
    for (int cq = 0; cq < 7; ++cq) {
        #pragma unroll
        for (int p = 0; p < 4; ++p) {
            waitvm<15>();
            __builtin_amdgcn_s_barrier();
            asm volatile("" ::: "memory");
            compute(p);
            asm volatile("s_waitcnt lgkmcnt(0)" ::: "memory");
            __builtin_amdgcn_s_barrier();
            asm volatile("" ::: "memory");
            const int c = cq * 4 + p + 4;
            loadB(p, c);
            stageA(p, c);
        }
    }
    // ---- tail: chunks 28..31, peeled waits ----
    waitvm<15>(); __builtin_amdgcn_s_barrier(); asm volatile("" ::: "memory"); compute(0);
    waitvm<10>(); __builtin_amdgcn_s_barrier(); asm volatile("" ::: "memory"); compute(1);
    waitvm<5>();  __builtin_amdgcn_s_barrier(); asm volatile("" ::: "memory"); compute(2);
    waitvm<0>();  __builtin_amdgcn_s_barrier(); asm volatile("" ::: "memory"); compute(3);
    __syncthreads();

    // ---- logits -> LDS (each (row,e) written once) ----
    float* lgs = &smem[0][0];                   // [32][68] = 8.7 KB
    #pragma unroll
    for (int j = 0; j < 4; ++j)
        lgs[(16 * rsel + k8 * 4 + j) * LPAD + e0w + l15] = acc[j];
    __syncthreads();

    // ---- per-row top-2 + softmax (waves 0..3, 8 rows each) ----
    if (wv < 4) {
        const int row = wv * 8 + (lane >> 3);
        const int seg = lane & 7;
        const float* rp = &lgs[row * LPAD + seg * 8];
        const float4 a  = *reinterpret_cast<const float4*>(rp);
        const float4 bq = *reinterpret_cast<const float4*>(rp + 4);
        const float sv[8] = {a.x, a.y, a.z, a.w, bq.x, bq.y, bq.z, bq.w};
        float m1 = sv[0]; int i1 = seg * 8;
        float m2 = -INFINITY; int i2 = 0;
        #pragma unroll
        for (int j = 1; j < 8; ++j) {
            const float v = sv[j]; const int idx = seg * 8 + j;
            if (v > m1)      { m2 = m1; i2 = i1; m1 = v; i1 = idx; }
            else if (v > m2) { m2 = v;  i2 = idx; }
        }
        #pragma unroll
        for (int d = 1; d < 8; d <<= 1) {
            const float M1 = __shfl_xor(m1, d); const int I1 = __shfl_xor(i1, d);
            const float M2 = __shfl_xor(m2, d); const int I2 = __shfl_xor(i2, d);
            const bool sw = (M1 > m1) || (M1 == m1 && I1 < i1);
            const float a1 = sw ? M1 : m1; const int j1 = sw ? I1 : i1;
            const float b1 = sw ? m1 : M1; const int kx = sw ? i1 : I1;
            const float a2 = sw ? M2 : m2; const int j2 = sw ? I2 : i2;
            const bool t2 = (b1 > a2) || (b1 == a2 && kx < j2);
            m1 = a1; i1 = j1;
            m2 = t2 ? b1 : a2; i2 = t2 ? kx : j2;
        }
        if (seg == 0) {
            const float e2v = expf(m2 - m1);
            const float sm  = 1.0f + e2v;
            const long  r   = row0 + row;
            const long  off = (long)nrows * 2;
            out[2 * r + 0]       = (float)i1;
            out[2 * r + 1]       = (float)i2;
            out[off + 2 * r + 0] = 1.0f / sm;
            out[off + 2 * r + 1] = e2v / sm;
        }
    }
}

extern "C" void kernel_launch(void* const* d_in, const int* in_sizes, int n_in,
                              void* d_out, int out_size, void* d_ws, size_t ws_size,
                              hipStream_t stream) {
    const float* x = (const float*)d_in[0];
    const float* w = (const float*)d_in[1];
    float* out = (float*)d_out;
    short* wsb = (short*)d_ws;
    const int nrows = in_sizes[0] / D_DIM;            // 16384
    const int grid  = nrows / BM;                     // 512
    const bool packed = ws_size >= (size_t)(E_DIM * D_DIM) * 2 * sizeof(short);

    if (packed) {
        hipLaunchKernelGGL(pack_w, dim3(E_DIM * D_DIM / 256), dim3(256), 0, stream, w, wsb);
        hipLaunchKernelGGL(router_v8<true>, dim3(grid), dim3(512), 0, stream,
                           x, w, wsb, out, nrows);
    } else {
        hipLaunchKernelGGL(router_v8<false>, dim3(grid), dim3(512), 0, stream,
                           x, w, wsb, out, nrows);
    }
}